// Round 7
// baseline (132.097 us; speedup 1.0000x reference)
//
#include <hip/hip_runtime.h>
#include <hip/hip_bf16.h>
#include <math.h>

// ---------------- problem constants ----------------
#define D_MODEL   1024
#define K_TOT     32
#define N_DECAY   28
#define M_DIM     8
#define KS        4
#define H_DIM     32
#define DIM_K     1024
#define DIM_MEM   1056
#define DIM_Q     2048
#define TOTAL_DIM 3104
#define NPAD_IN   3328          // 13 * 256
#define B_SZ      2
#define L_SEQ     2048
#define BL_TOT    4096

#define KG_CNT    4             // k-groups of 8
#define NCHUNK    64
#define CHUNK_L   32            // L_SEQ / NCHUNK

typedef __attribute__((ext_vector_type(8))) __bf16 bf16x8;
typedef __attribute__((ext_vector_type(4))) __bf16 bf16x4;
typedef __attribute__((ext_vector_type(4))) float  f32x4;

// ================= GEMM1: 256^2, reg-staged (no LDS-DMA), dbuf =============
// C = A[M,K] * Bt[Npad,K]; BK=64, 512 thr (8 waves 2Mx4N).
// Staging: coalesced global_load_dwordx4 -> VGPR (1 tile in flight) ->
// ds_write_b128 with XOR-swizzled physical slot. Raw barriers, no vmcnt drain.
// Split epilogue: col<1056 -> f32 z_mem, [1056,3104) -> bf16 q_b.
__global__ __launch_bounds__(512) void gemm_big(const __bf16* __restrict__ A,
                                                const __bf16* __restrict__ Bt,
                                                float* __restrict__ C,
                                                __bf16* __restrict__ Cq,
                                                int Kdim, int gx) {
    __shared__ __bf16 lds[2][2][256 * 64];   // [buf][A=0/B=1]  128 KiB

    const int tid  = threadIdx.x;
    const int w    = tid >> 6;
    const int lane = tid & 63;
    const int l15  = lane & 15;
    const int l16  = lane >> 4;
    const int wm   = w >> 2;                // 0..1
    const int wn   = w & 3;                 // 0..3

    const int nwg = gridDim.x;
    int lin = blockIdx.x;
    lin = (lin & 7) * (nwg >> 3) + (lin >> 3);
    const int bx = lin % gx, by = lin / gx;
    const int r0 = by * 256, c0 = bx * 256;

    const int strow  = tid >> 3;            // 0..63 (row within 64-row group)
    const int stslot = tid & 7;             // logical 16B slot (linear global!)

    f32x4 acc[8][4] = {};
    bf16x8 stA[4], stB[4];
    const int NT = Kdim / 64;               // 16

#define LOAD_ST(T)                                                             \
    _Pragma("unroll")                                                          \
    for (int j = 0; j < 4; j++) {                                              \
        const int r_ = j * 64 + strow;                                         \
        stA[j] = *(const bf16x8*)(A + (size_t)(r0 + r_) * Kdim + (T) * 64      \
                                  + stslot * 8);                               \
        stB[j] = *(const bf16x8*)(Bt + (size_t)(c0 + r_) * Kdim + (T) * 64     \
                                  + stslot * 8);                               \
    }

#define DSWRITE(BUF)                                                           \
    _Pragma("unroll")                                                          \
    for (int j = 0; j < 4; j++) {                                              \
        const int r_ = j * 64 + strow;                                         \
        const int p_ = stslot ^ (r_ & 7);                                      \
        *(bf16x8*)&lds[BUF][0][r_ * 64 + p_ * 8] = stA[j];                     \
        *(bf16x8*)&lds[BUF][1][r_ * 64 + p_ * 8] = stB[j];                     \
    }

    // prologue: tiles 0,1 into LDS; tile 2 in regs
    LOAD_ST(0); DSWRITE(0);
    LOAD_ST(1); DSWRITE(1);
    LOAD_ST(2);
    asm volatile("s_waitcnt lgkmcnt(0)" ::: "memory");
    __builtin_amdgcn_s_barrier();
    __builtin_amdgcn_sched_barrier(0);

    for (int t = 0; t < NT; ++t) {
        const int cur = t & 1;
        const __bf16* As_ = &lds[cur][0][0];
        const __bf16* Bs_ = &lds[cur][1][0];

#pragma unroll
        for (int kk = 0; kk < 2; kk++) {
            bf16x8 a[8], b[4];
#pragma unroll
            for (int ni = 0; ni < 4; ni++) {
                const int col  = wn * 64 + ni * 16 + l15;
                const int slot = (kk * 4 + l16) ^ (col & 7);
                b[ni] = *(const bf16x8*)&Bs_[col * 64 + slot * 8];
            }
#pragma unroll
            for (int mi = 0; mi < 8; mi++) {
                const int row  = wm * 128 + mi * 16 + l15;
                const int slot = (kk * 4 + l16) ^ (row & 7);
                a[mi] = *(const bf16x8*)&As_[row * 64 + slot * 8];
            }
            __builtin_amdgcn_s_setprio(1);
#pragma unroll
            for (int mi = 0; mi < 8; mi++)
#pragma unroll
                for (int ni = 0; ni < 4; ni++)
                    acc[mi][ni] = __builtin_amdgcn_mfma_f32_16x16x32_bf16(
                        a[mi], b[ni], acc[mi][ni], 0, 0, 0);
            __builtin_amdgcn_s_setprio(0);
        }
        // barrier X: all waves done reading lds[cur]
        asm volatile("s_waitcnt lgkmcnt(0)" ::: "memory");
        __builtin_amdgcn_s_barrier();
        __builtin_amdgcn_sched_barrier(0);
        // write tile t+2 into freed buffer; issue loads for t+3
        if (t + 2 < NT) { DSWRITE(cur); }
        if (t + 3 < NT) { LOAD_ST(t + 3); }
        __builtin_amdgcn_sched_barrier(0);
        asm volatile("s_waitcnt lgkmcnt(0)" ::: "memory");
        __builtin_amdgcn_s_barrier();   // barrier Y: tile t+1 buffer stable
        __builtin_amdgcn_sched_barrier(0);
    }
#undef LOAD_ST
#undef DSWRITE

    // epilogue: C/D layout col=lane&15, row=(lane>>4)*4+q
#pragma unroll
    for (int mi = 0; mi < 8; mi++) {
#pragma unroll
        for (int ni = 0; ni < 4; ni++) {
            const int col = c0 + wn * 64 + ni * 16 + l15;
            const int row = r0 + wm * 128 + mi * 16 + l16 * 4;
            if (col < DIM_MEM) {
#pragma unroll
                for (int q = 0; q < 4; q++)
                    C[(size_t)(row + q) * DIM_MEM + col] = acc[mi][ni][q];
            } else if (col < TOTAL_DIM) {
#pragma unroll
                for (int q = 0; q < 4; q++)
                    Cq[(size_t)(row + q) * DIM_Q + (col - DIM_MEM)] =
                        (__bf16)acc[mi][ni][q];
            }
        }
    }
}

// ================= GEMM2: 128^2, reg-staged, dbuf ===========================
__global__ __launch_bounds__(512) void gemm_mid(const __bf16* __restrict__ A,
                                                const __bf16* __restrict__ Bt,
                                                float* __restrict__ C,
                                                int Ndim, int Kdim, int gx) {
    __shared__ __bf16 lds[2][2][128 * 64];   // 64 KiB

    const int tid  = threadIdx.x;
    const int w    = tid >> 6;
    const int lane = tid & 63;
    const int l15  = lane & 15;
    const int l16  = lane >> 4;
    const int wm   = w >> 1;                // 0..3 (M, 32 rows each)
    const int wn   = w & 1;                 // 0..1 (N, 64 cols each)

    const int nwg = gridDim.x;
    int lin = blockIdx.x;
    lin = (lin & 7) * (nwg >> 3) + (lin >> 3);
    const int bx = lin % gx, by = lin / gx;
    const int r0 = by * 128, c0 = bx * 128;

    const int strow  = tid >> 3;            // 0..63
    const int stslot = tid & 7;

    f32x4 acc[2][4] = {};
    bf16x8 stA[2], stB[2];
    const int NT = Kdim / 64;

#define LOAD_ST(T)                                                             \
    _Pragma("unroll")                                                          \
    for (int j = 0; j < 2; j++) {                                              \
        const int r_ = j * 64 + strow;                                         \
        stA[j] = *(const bf16x8*)(A + (size_t)(r0 + r_) * Kdim + (T) * 64      \
                                  + stslot * 8);                               \
        stB[j] = *(const bf16x8*)(Bt + (size_t)(c0 + r_) * Kdim + (T) * 64     \
                                  + stslot * 8);                               \
    }

#define DSWRITE(BUF)                                                           \
    _Pragma("unroll")                                                          \
    for (int j = 0; j < 2; j++) {                                              \
        const int r_ = j * 64 + strow;                                         \
        const int p_ = stslot ^ (r_ & 7);                                      \
        *(bf16x8*)&lds[BUF][0][r_ * 64 + p_ * 8] = stA[j];                     \
        *(bf16x8*)&lds[BUF][1][r_ * 64 + p_ * 8] = stB[j];                     \
    }

    LOAD_ST(0); DSWRITE(0);
    LOAD_ST(1); DSWRITE(1);
    LOAD_ST(2);
    asm volatile("s_waitcnt lgkmcnt(0)" ::: "memory");
    __builtin_amdgcn_s_barrier();
    __builtin_amdgcn_sched_barrier(0);

    for (int t = 0; t < NT; ++t) {
        const int cur = t & 1;
        const __bf16* As_ = &lds[cur][0][0];
        const __bf16* Bs_ = &lds[cur][1][0];

#pragma unroll
        for (int kk = 0; kk < 2; kk++) {
            bf16x8 a[2], b[4];
#pragma unroll
            for (int ni = 0; ni < 4; ni++) {
                const int col  = wn * 64 + ni * 16 + l15;
                const int slot = (kk * 4 + l16) ^ (col & 7);
                b[ni] = *(const bf16x8*)&Bs_[col * 64 + slot * 8];
            }
#pragma unroll
            for (int mi = 0; mi < 2; mi++) {
                const int row  = wm * 32 + mi * 16 + l15;
                const int slot = (kk * 4 + l16) ^ (row & 7);
                a[mi] = *(const bf16x8*)&As_[row * 64 + slot * 8];
            }
            __builtin_amdgcn_s_setprio(1);
#pragma unroll
            for (int mi = 0; mi < 2; mi++)
#pragma unroll
                for (int ni = 0; ni < 4; ni++)
                    acc[mi][ni] = __builtin_amdgcn_mfma_f32_16x16x32_bf16(
                        a[mi], b[ni], acc[mi][ni], 0, 0, 0);
            __builtin_amdgcn_s_setprio(0);
        }
        asm volatile("s_waitcnt lgkmcnt(0)" ::: "memory");
        __builtin_amdgcn_s_barrier();
        __builtin_amdgcn_sched_barrier(0);
        if (t + 2 < NT) { DSWRITE(cur); }
        if (t + 3 < NT) { LOAD_ST(t + 3); }
        __builtin_amdgcn_sched_barrier(0);
        asm volatile("s_waitcnt lgkmcnt(0)" ::: "memory");
        __builtin_amdgcn_s_barrier();
        __builtin_amdgcn_sched_barrier(0);
    }
#undef LOAD_ST
#undef DSWRITE

#pragma unroll
    for (int mi = 0; mi < 2; mi++) {
#pragma unroll
        for (int ni = 0; ni < 4; ni++) {
            const int col = c0 + wn * 64 + ni * 16 + l15;
            const int row = r0 + wm * 32 + mi * 16 + l16 * 4;
#pragma unroll
            for (int q = 0; q < 4; q++)
                C[(size_t)(row + q) * Ndim + col] = acc[mi][ni][q];
        }
    }
}

// ---------------- straight cast fp32 -> bf16 ----------------
__global__ __launch_bounds__(256) void cast_bf16(const float* __restrict__ in,
                                                 __bf16* __restrict__ out, int n4) {
    const int i = blockIdx.x * blockDim.x + threadIdx.x;
    if (i >= n4) return;
    const float4 v = ((const float4*)in)[i];
    bf16x4 o;
    o.x = (__bf16)v.x; o.y = (__bf16)v.y; o.z = (__bf16)v.z; o.w = (__bf16)v.w;
    ((bf16x4*)out)[i] = o;
}

// ---------------- transpose-cast: W[K,N] f32 -> Wt[Npad,K] bf16 ----------------
__global__ __launch_bounds__(256) void transpose_cast(const float* __restrict__ W,
                                                      __bf16* __restrict__ Wt,
                                                      int Kdim, int Ndim, int Npad) {
    __shared__ float tile[32][33];
    const int n0 = blockIdx.x * 32, k0 = blockIdx.y * 32;
    const int tx = threadIdx.x & 31, ty = threadIdx.x >> 5;
#pragma unroll
    for (int i = 0; i < 32; i += 8) {
        float v = 0.f;
        if (n0 + tx < Ndim) v = W[(size_t)(k0 + ty + i) * Ndim + n0 + tx];
        tile[ty + i][tx] = v;
    }
    __syncthreads();
#pragma unroll
    for (int i = 0; i < 32; i += 8) {
        const int n = n0 + ty + i;
        if (n < Npad) Wt[(size_t)n * Kdim + k0 + tx] = (__bf16)tile[tx][ty + i];
    }
}

// ---------------- depthwise causal conv + gate weights ----------------
__global__ __launch_bounds__(256) void conv_pw(const float* __restrict__ z_mem,
                                               const float* __restrict__ conv_k,
                                               const float* __restrict__ score_scale,
                                               const float* __restrict__ decay_slopes,
                                               const float* __restrict__ anchor_slopes,
                                               __bf16* __restrict__ k_val,
                                               float* __restrict__ p_w) {
    const int bl = blockIdx.x;
    const int l = bl & (L_SEQ - 1);
    const int b = bl >> 11;
    const int t = threadIdx.x;

    {
        const int c = 4 * t;
        float4 acc = {0.f, 0.f, 0.f, 0.f};
#pragma unroll
        for (int s = 0; s < KS; s++) {
            const int tl = l - (KS - 1) + s;
            if (tl >= 0) {
                const float4 ck = *(const float4*)&conv_k[s * DIM_MEM + c];
                const float4 zv = *(const float4*)&z_mem[((size_t)b * L_SEQ + tl) * DIM_MEM + c];
                acc.x = fmaf(ck.x, zv.x, acc.x);
                acc.y = fmaf(ck.y, zv.y, acc.y);
                acc.z = fmaf(ck.z, zv.z, acc.z);
                acc.w = fmaf(ck.w, zv.w, acc.w);
            }
        }
        bf16x4 o;
        o.x = (__bf16)acc.x; o.y = (__bf16)acc.y;
        o.z = (__bf16)acc.z; o.w = (__bf16)acc.w;
        *(bf16x4*)&k_val[(size_t)bl * DIM_K + c] = o;
    }

    if (t < 8) {
        const int c = DIM_MEM - K_TOT + 4 * t;
        float acc[4] = {0.f, 0.f, 0.f, 0.f};
#pragma unroll
        for (int s = 0; s < KS; s++) {
            const int tl = l - (KS - 1) + s;
            if (tl >= 0) {
                const float4 ck = *(const float4*)&conv_k[s * DIM_MEM + c];
                const float4 zv = *(const float4*)&z_mem[((size_t)b * L_SEQ + tl) * DIM_MEM + c];
                acc[0] = fmaf(ck.x, zv.x, acc[0]);
                acc[1] = fmaf(ck.y, zv.y, acc[1]);
                acc[2] = fmaf(ck.z, zv.z, acc[2]);
                acc[3] = fmaf(ck.w, zv.w, acc[3]);
            }
        }
#pragma unroll
        for (int j = 0; j < 4; j++) {
            const int k = 4 * t + j;
            const float lp = fminf(fmaxf(score_scale[k] * acc[j], -20.f), 20.f);
            float lt;
            if (k < N_DECAY) {
                const float sd = log1pf(__expf(decay_slopes[k]));
                lt = -sd * (float)(L_SEQ - 1 - l);
            } else {
                const float sa = log1pf(__expf(anchor_slopes[k - N_DECAY]));
                lt = -sa * (float)l;
            }
            p_w[(size_t)bl * K_TOT + k] = __expf(lp + lt);
        }
    }
}

// ---------------- phase 1: per-chunk totals (rotation over m) ----------------
__global__ __launch_bounds__(256) void chunk_sums(const __bf16* __restrict__ k_val,
                                                  const float* __restrict__ p_w,
                                                  const float* __restrict__ theta,
                                                  float* __restrict__ csum,
                                                  float* __restrict__ cden) {
    const int idx = blockIdx.x;
    const int c = idx & (NCHUNK - 1);
    const int bkg = idx / NCHUNK;
    const int kg = bkg & (KG_CNT - 1);
    const int b = bkg / KG_CNT;
    const int t = threadIdx.x;
    const int kl = t >> 5;
    const int h = t & 31;
    const int k = kg * 8 + kl;
    const int bk = b * K_TOT + k;

    const float A0 = theta[(k * H_DIM + h) * M_DIM + 0];
    const float Dt = theta[(k * H_DIM + h) * M_DIM + 1] - A0;

    float nre[M_DIM] = {}, nim[M_DIM] = {};
    float den = 0.f;
    const int l0 = c * CHUNK_L;
#pragma unroll 2
    for (int i = 0; i < CHUNK_L; i++) {
        const size_t bl = (size_t)b * L_SEQ + (l0 + i);
        const float p  = p_w[bl * K_TOT + k];
        const float kv = (float)k_val[bl * DIM_K + k * H_DIM + h];
        float cc = __cosf(kv * A0), ss = __sinf(kv * A0);
        const float cd = __cosf(kv * Dt), sd = __sinf(kv * Dt);
#pragma unroll
        for (int m = 0; m < M_DIM; m++) {
            nre[m] = fmaf(p, cc, nre[m]);
            nim[m] = fmaf(p, ss, nim[m]);
            const float c2 = fmaf(cc, cd, -(ss * sd));
            ss = fmaf(ss, cd, cc * sd);
            cc = c2;
        }
        den += p;
    }

    float* base = &csum[(((size_t)bk * NCHUNK + c) * 256 + h * M_DIM) * 2];
#pragma unroll
    for (int j = 0; j < 4; j++) {
        f32x4 v = { nre[2 * j], nim[2 * j], nre[2 * j + 1], nim[2 * j + 1] };
        ((f32x4*)base)[j] = v;
    }
    if (h == 0) cden[bk * NCHUNK + c] = den;
}

// ---------------- phase 2: exclusive prefix over chunks ----------------
__global__ __launch_bounds__(256) void chunk_prefix(float* __restrict__ csum,
                                                    float* __restrict__ cden) {
    const int bk = blockIdx.x;
    const int t = threadIdx.x;

    if (t < 64) {
        const float orig = cden[bk * NCHUNK + t];
        float v = orig;
#pragma unroll
        for (int d = 1; d < 64; d <<= 1) {
            const float u = __shfl_up(v, d);
            if (t >= d) v += u;
        }
        cden[bk * NCHUNK + t] = v - orig;
    }

    float run_re = 0.f, run_im = 0.f;
    for (int c = 0; c < NCHUNK; c++) {
        float2* p = (float2*)&csum[(((size_t)bk * NCHUNK + c) * 256 + t) * 2];
        const float2 v = *p;
        *p = make_float2(run_re, run_im);
        run_re += v.x;
        run_im += v.y;
    }
}

// ---------------- phase 3: replay + output epilogue ----------------
__global__ __launch_bounds__(256) void scan_out(const __bf16* __restrict__ q_b,
                                                const __bf16* __restrict__ k_val,
                                                const float* __restrict__ p_w,
                                                const float* __restrict__ theta,
                                                const float* __restrict__ csum,
                                                const float* __restrict__ cden,
                                                const float* __restrict__ W_re,
                                                const float* __restrict__ W_im,
                                                const float* __restrict__ norm_scale,
                                                __bf16* __restrict__ y) {
    const int idx = blockIdx.x;
    const int c = idx & (NCHUNK - 1);
    const int bkg = idx / NCHUNK;
    const int kg = bkg & (KG_CNT - 1);
    const int b = bkg / KG_CNT;
    const int t = threadIdx.x;
    const int kl = t >> 5;
    const int h = t & 31;
    const int k = kg * 8 + kl;
    const int bk = b * K_TOT + k;

    const float A0 = theta[(k * H_DIM + h) * M_DIM + 0];
    const float Dt = theta[(k * H_DIM + h) * M_DIM + 1] - A0;

    float nre[M_DIM], nim[M_DIM];
    {
        const float* base = &csum[(((size_t)bk * NCHUNK + c) * 256 + h * M_DIM) * 2];
#pragma unroll
        for (int j = 0; j < 4; j++) {
            const f32x4 v = ((const f32x4*)base)[j];
            nre[2 * j] = v.x; nim[2 * j] = v.y;
            nre[2 * j + 1] = v.z; nim[2 * j + 1] = v.w;
        }
    }
    float den = cden[bk * NCHUNK + c];

    const float wsc_re = norm_scale[h] * W_re[h * H_DIM + h];
    const float wsc_im = norm_scale[H_DIM + h] * W_im[h * H_DIM + h];

    const int l0 = c * CHUNK_L;
    for (int i = 0; i < CHUNK_L; i++) {
        const size_t bl = (size_t)b * L_SEQ + (l0 + i);
        const float p  = p_w[bl * K_TOT + k];
        const float kv = (float)k_val[bl * DIM_K + k * H_DIM + h];

        const __bf16* qp = &q_b[bl * DIM_Q + (size_t)(kg * H_DIM + h) * 16];
        const bf16x8 q0 = *(const bf16x8*)qp;
        const bf16x8 q1 = *(const bf16x8*)(qp + 8);

        float cc = __cosf(kv * A0), ss = __sinf(kv * A0);
        const float cd = __cosf(kv * Dt), sd = __sinf(kv * Dt);

        float ore = 0.f, oim = 0.f;
#pragma unroll
        for (int m = 0; m < M_DIM; m++) {
            nre[m] = fmaf(p, cc, nre[m]);
            nim[m] = fmaf(p, ss, nim[m]);
            const float qr = (m < 4) ? (float)q0[2 * (m & 3)]     : (float)q1[2 * (m & 3)];
            const float qi = (m < 4) ? (float)q0[2 * (m & 3) + 1] : (float)q1[2 * (m & 3) + 1];
            ore = fmaf(nre[m], qr, fmaf(nim[m], qi, ore));
            oim = fmaf(nim[m], qr, fmaf(-nre[m], qi, oim));
            const float c2 = fmaf(cc, cd, -(ss * sd));
            ss = fmaf(ss, cd, cc * sd);
            cc = c2;
        }
        den += p;
        const float inv = __builtin_amdgcn_rcpf(fmaxf(den, 1e-4f));

        const float v = (ore * wsc_re + oim * wsc_im) * inv;
        const float yv = v * __builtin_amdgcn_rcpf(1.0f + __expf(-v));
        y[bl * DIM_K + k * H_DIM + h] = (__bf16)yv;
    }
}

// ---------------- launch ----------------
extern "C" void kernel_launch(void* const* d_in, const int* in_sizes, int n_in,
                              void* d_out, int out_size, void* d_ws, size_t ws_size,
                              hipStream_t stream) {
    const float* x            = (const float*)d_in[0];
    const float* W_in         = (const float*)d_in[1];
    const float* conv_k       = (const float*)d_in[2];
    const float* theta        = (const float*)d_in[3];
    const float* decay_slopes = (const float*)d_in[4];
    const float* anchor_slopes= (const float*)d_in[5];
    const float* score_scale  = (const float*)d_in[6];
    const float* W_re         = (const float*)d_in[7];
    const float* W_im         = (const float*)d_in[8];
    const float* norm_scale   = (const float*)d_in[9];
    const float* W_out        = (const float*)d_in[10];
    float* out = (float*)d_out;

    float* ws = (float*)d_ws;
    size_t off = 0;
    float* z_mem  = ws + off; off += (size_t)BL_TOT * DIM_MEM;
    float* p_w    = ws + off; off += (size_t)BL_TOT * K_TOT;
    float* csum   = ws + off; off += (size_t)B_SZ * K_TOT * NCHUNK * 256 * 2;
    float* cden   = ws + off; off += (size_t)B_SZ * K_TOT * NCHUNK;
    __bf16* k_val   = (__bf16*)(ws + off); off += (size_t)BL_TOT * DIM_K / 2;
    __bf16* x_b     = (__bf16*)(ws + off); off += (size_t)BL_TOT * D_MODEL / 2;
    __bf16* W_in_T  = (__bf16*)(ws + off); off += (size_t)NPAD_IN * D_MODEL / 2;
    __bf16* W_out_T = (__bf16*)(ws + off); off += (size_t)D_MODEL * D_MODEL / 2;
    __bf16* y_b     = (__bf16*)(ws + off); off += (size_t)BL_TOT * DIM_K / 2;
    __bf16* q_b     = (__bf16*)(ws + off); off += (size_t)BL_TOT * DIM_Q / 2;

    cast_bf16<<<(BL_TOT * D_MODEL / 4 + 255) / 256, 256, 0, stream>>>(
        x, x_b, BL_TOT * D_MODEL / 4);
    {
        dim3 g(NPAD_IN / 32, D_MODEL / 32);
        transpose_cast<<<g, 256, 0, stream>>>(W_in, W_in_T, D_MODEL, TOTAL_DIM, NPAD_IN);
    }
    {
        dim3 g(D_MODEL / 32, D_MODEL / 32);
        transpose_cast<<<g, 256, 0, stream>>>(W_out, W_out_T, D_MODEL, D_MODEL, D_MODEL);
    }

    // 1) z = x @ W_in (reg-staged 256^2, split epilogue)
    gemm_big<<<(NPAD_IN / 256) * (BL_TOT / 256), 512, 0, stream>>>(
        x_b, W_in_T, z_mem, q_b, D_MODEL, NPAD_IN / 256);

    // 2) depthwise conv + p_w
    conv_pw<<<BL_TOT, 256, 0, stream>>>(z_mem, conv_k, score_scale, decay_slopes,
                                        anchor_slopes, k_val, p_w);
    // 3) blocked scan
    chunk_sums<<<B_SZ * KG_CNT * NCHUNK, 256, 0, stream>>>(k_val, p_w, theta, csum, cden);
    chunk_prefix<<<B_SZ * K_TOT, 256, 0, stream>>>(csum, cden);
    scan_out<<<B_SZ * KG_CNT * NCHUNK, 256, 0, stream>>>(q_b, k_val, p_w, theta, csum,
                                                         cden, W_re, W_im, norm_scale, y_b);
    // 4) out = y @ W_out (reg-staged 128^2)
    gemm_mid<<<(D_MODEL / 128) * (BL_TOT / 128), 512, 0, stream>>>(
        y_b, W_out_T, out, D_MODEL, D_MODEL, D_MODEL / 128);
}